// Round 1
// baseline (109.021 us; speedup 1.0000x reference)
//
#include <hip/hip_runtime.h>

// Problem constants (B=2, H=4 -> NBH=8; Tq=Tk=512; D=64; HID=128)
#define T    512
#define D    64
#define HID  128
#define NBH  8

// ---------------------------------------------------------------------------
// Phase A: qh[bh][c][i] = b1[c] + sum_d q[bh][i][d] * W1[d][c]   (src==0)
//          kh[bh][c][j] =         sum_d k[bh][j][d] * W1[64+d][c] (src==1)
// Stored TRANSPOSED ([c][i] with i contiguous) so phase B can stage LDS tiles
// with coalesced loads and read float4 fragments along i/j.
// grid: 8 bh x 2 src x 8 row-chunks = 128 blocks, 256 threads.
// ---------------------------------------------------------------------------
__global__ __launch_bounds__(256) void proj_kernel(
    const float* __restrict__ q, const float* __restrict__ k,
    const float* __restrict__ W1, const float* __restrict__ b1,
    float* __restrict__ qh_t, float* __restrict__ kh_t)
{
    const int bid   = blockIdx.x;       // [0,128)
    const int bh    = bid >> 4;
    const int src   = (bid >> 3) & 1;
    const int chunk = bid & 7;

    const float* __restrict__ X   = (src == 0) ? q : k;
    float* __restrict__ outp      = (src == 0) ? qh_t : kh_t;

    // W1 half, transposed to [c][d]; stride 68 floats = 272 B (16B aligned, +4 pad
    // breaks the d%32 bank collision on the staging writes).
    __shared__ float w1t[HID][68];

    const int tid = threadIdx.x;
    for (int idx = tid; idx < D * HID; idx += 256) {
        const int d = idx >> 7;          // idx / 128
        const int c = idx & (HID - 1);
        w1t[c][d] = W1[(src * D + d) * HID + c];
    }
    __syncthreads();

    const int r  = tid & 63;             // lane -> row (stores coalesce over lanes)
    const int cg = tid >> 6;             // wave id -> c-group (wave-uniform c)
    const int i  = chunk * 64 + r;

    // Pull this thread's input row into registers (16 x float4 = 64 VGPR).
    float xr[D];
    const float4* xrow = (const float4*)(X + (size_t)(bh * T + i) * D);
    #pragma unroll
    for (int t = 0; t < D / 4; ++t) {
        const float4 v = xrow[t];
        xr[4*t+0] = v.x; xr[4*t+1] = v.y; xr[4*t+2] = v.z; xr[4*t+3] = v.w;
    }

    for (int cc = 0; cc < 32; ++cc) {
        const int c = cg * 32 + cc;      // wave-uniform -> LDS broadcast reads
        float acc = (src == 0) ? b1[c] : 0.0f;
        const float4* wrow = (const float4*)(&w1t[c][0]);
        #pragma unroll
        for (int t = 0; t < D / 4; ++t) {
            const float4 w = wrow[t];
            acc += xr[4*t+0]*w.x + xr[4*t+1]*w.y + xr[4*t+2]*w.z + xr[4*t+3]*w.w;
        }
        // Transposed store: lanes span consecutive i -> 256 B coalesced per c.
        outp[(size_t)(bh * HID + c) * T + i] = acc;
    }
}

// ---------------------------------------------------------------------------
// Phase B: s[bh][i][j] = b2 + sum_c W2[c] * relu(qh[bh][c][i] + kh[bh][c][j])
// 64x64 output tile per block, 256 threads, 4x4 accumulator per thread.
// LDS: qt/kt tiles [128 c][64 i] = 2 x 32 KB = 64 KB -> 2 blocks/CU.
// Per c per thread: 2 x ds_read_b128 (broadcast groups of 16/4 lanes,
// conflict-free or 2-way) + 48 VALU (add, max, fma x 16 pairs).
// grid: 8 bh x 8 it x 8 jt = 512 blocks.
// ---------------------------------------------------------------------------
__global__ __launch_bounds__(256) void score_kernel(
    const float* __restrict__ qh_t, const float* __restrict__ kh_t,
    const float* __restrict__ W2, const float* __restrict__ b2,
    float* __restrict__ out)
{
    const int bid = blockIdx.x;          // [0, 512)
    const int bh  = bid >> 6;
    const int it  = (bid >> 3) & 7;
    const int jt  = bid & 7;
    const int i0  = it * 64;
    const int j0  = jt * 64;

    __shared__ float qt[HID][64];
    __shared__ float kt[HID][64];

    const int tid = threadIdx.x;
    // Stage both tiles: 128 rows x 16 float4 each; coalesced 256 B per c-row.
    for (int idx = tid; idx < HID * 16; idx += 256) {
        const int c = idx >> 4;
        const int g = idx & 15;
        ((float4*)&qt[c][0])[g] =
            ((const float4*)(qh_t + (size_t)(bh * HID + c) * T + i0))[g];
        ((float4*)&kt[c][0])[g] =
            ((const float4*)(kh_t + (size_t)(bh * HID + c) * T + j0))[g];
    }
    __syncthreads();

    const int tx = tid & 15;             // j fragment
    const int ty = tid >> 4;             // i fragment

    float acc[4][4];
    #pragma unroll
    for (int m = 0; m < 4; ++m)
        #pragma unroll
        for (int n = 0; n < 4; ++n)
            acc[m][n] = 0.0f;

    #pragma unroll 4
    for (int c = 0; c < HID; ++c) {
        const float w = W2[c];           // wave-uniform -> scalar load
        const float4 qa = ((const float4*)&qt[c][0])[ty];
        const float4 kb = ((const float4*)&kt[c][0])[tx];
        const float qv[4] = {qa.x, qa.y, qa.z, qa.w};
        const float kv[4] = {kb.x, kb.y, kb.z, kb.w};
        #pragma unroll
        for (int m = 0; m < 4; ++m) {
            #pragma unroll
            for (int n = 0; n < 4; ++n) {
                const float u = qv[m] + kv[n];
                acc[m][n] += w * fmaxf(u, 0.0f);
            }
        }
    }

    const float bb = b2[0];
    #pragma unroll
    for (int m = 0; m < 4; ++m) {
        const int i = i0 + 4 * ty + m;
        float4 o;
        o.x = acc[m][0] + bb;
        o.y = acc[m][1] + bb;
        o.z = acc[m][2] + bb;
        o.w = acc[m][3] + bb;
        // lanes (tx) write 256 B contiguous per (ty,m) row -> coalesced.
        ((float4*)(out + (size_t)(bh * T + i) * T + j0))[tx] = o;
    }
}

extern "C" void kernel_launch(void* const* d_in, const int* in_sizes, int n_in,
                              void* d_out, int out_size, void* d_ws, size_t ws_size,
                              hipStream_t stream) {
    const float* q  = (const float*)d_in[0];
    const float* k  = (const float*)d_in[1];
    const float* W1 = (const float*)d_in[2];
    const float* b1 = (const float*)d_in[3];
    const float* W2 = (const float*)d_in[4];
    const float* b2 = (const float*)d_in[5];
    float* out = (float*)d_out;

    // Workspace: qh_t + kh_t, each 8*128*512 floats = 2 MB (4 MB total).
    float* qh_t = (float*)d_ws;
    float* kh_t = qh_t + (size_t)NBH * HID * T;

    proj_kernel<<<128, 256, 0, stream>>>(q, k, W1, b1, qh_t, kh_t);
    score_kernel<<<512, 256, 0, stream>>>(qh_t, kh_t, W2, b2, out);
}

// Round 2
// 92.125 us; speedup vs baseline: 1.1834x; 1.1834x over previous
//
#include <hip/hip_runtime.h>

// Problem constants (B=2, H=4 -> NBH=8; Tq=Tk=512; D=64; HID=128)
#define T    512
#define D    64
#define HID  128
#define NBH  8
#define NP   (HID / 2)   // 64 c-pairs

typedef _Float16 h2 __attribute__((ext_vector_type(2)));

#if __has_builtin(__builtin_amdgcn_fdot2)
#define HAVE_FDOT2 1
#else
#define HAVE_FDOT2 0
#endif

// ---------------------------------------------------------------------------
// Phase A: qh[bh][c][i] = b1[c] + sum_d q[bh][i][d] * W1[d][c]   (src==0)
//          kh[bh][c][j] =         sum_d k[bh][j][d] * W1[64+d][c] (src==1)
// Output stored as half2 pairs over c: ws[bh][p][i] = (h[2p][i], h[2p+1][i]),
// i contiguous -> phase B stages LDS tiles with coalesced 256 B row copies
// and consumes v_pk_* / v_dot2 operands directly.
// grid: 8 bh x 2 src x 8 row-chunks x 2 c-splits = 256 blocks, 256 threads.
// ---------------------------------------------------------------------------
__global__ __launch_bounds__(256) void proj_kernel(
    const float* __restrict__ q, const float* __restrict__ k,
    const float* __restrict__ W1, const float* __restrict__ b1,
    h2* __restrict__ qh_h, h2* __restrict__ kh_h)
{
    const int bid    = blockIdx.x;        // [0,256)
    const int bh     = bid >> 5;
    const int src    = (bid >> 4) & 1;
    const int chunk  = (bid >> 1) & 7;
    const int csplit = bid & 1;
    const int base_c = csplit * 64;

    const float* __restrict__ X = (src == 0) ? q : k;
    h2* __restrict__ outp       = (src == 0) ? qh_h : kh_h;

    // 64 c-rows of W1 half, transposed to [cc][d]; stride 68 floats keeps
    // 16 B alignment (272 B) and breaks pow-2 bank stride on staging writes.
    __shared__ float w1t[64][68];

    const int tid = threadIdx.x;
    for (int idx = tid; idx < 64 * 64; idx += 256) {
        const int cc = idx & 63;          // consecutive -> coalesced global read
        const int d  = idx >> 6;
        w1t[cc][d] = W1[(src * D + d) * HID + base_c + cc];
    }
    __syncthreads();

    const int r  = tid & 63;              // lane -> row (stores coalesce)
    const int cg = tid >> 6;              // wave -> 16-c group (wave-uniform)
    const int i  = chunk * 64 + r;

    // This thread's input row in registers (64 VGPR).
    float xr[D];
    const float4* xrow = (const float4*)(X + (size_t)(bh * T + i) * D);
    #pragma unroll
    for (int t = 0; t < D / 4; ++t) {
        const float4 v = xrow[t];
        xr[4*t+0] = v.x; xr[4*t+1] = v.y; xr[4*t+2] = v.z; xr[4*t+3] = v.w;
    }

    #pragma unroll
    for (int pp = 0; pp < 8; ++pp) {
        const int cc0 = cg * 16 + 2 * pp;        // wave-uniform -> LDS broadcast
        float acc0 = (src == 0) ? b1[base_c + cc0]     : 0.0f;
        float acc1 = (src == 0) ? b1[base_c + cc0 + 1] : 0.0f;
        const float4* w0 = (const float4*)(&w1t[cc0][0]);
        const float4* w1 = (const float4*)(&w1t[cc0 + 1][0]);
        #pragma unroll
        for (int t = 0; t < D / 4; ++t) {
            const float4 a = w0[t];
            const float4 b = w1[t];
            acc0 += xr[4*t+0]*a.x + xr[4*t+1]*a.y + xr[4*t+2]*a.z + xr[4*t+3]*a.w;
            acc1 += xr[4*t+0]*b.x + xr[4*t+1]*b.y + xr[4*t+2]*b.z + xr[4*t+3]*b.w;
        }
        h2 v;
        v.x = (_Float16)acc0;
        v.y = (_Float16)acc1;
        const int p = csplit * 32 + cg * 8 + pp;  // global pair index [0,64)
        outp[(size_t)(bh * NP + p) * T + i] = v;  // lanes span i -> 256 B coalesced
    }
}

// ---------------------------------------------------------------------------
// Phase B: s[bh][i][j] = b2 + sum_c W2[c] * relu(qh[bh][c][i] + kh[bh][c][j])
// 64x64 output tile, 256 threads, 4x4 fp32 acc per thread.
// Packed-fp16 inner loop: per c-PAIR per (m,n): v_pk_add_f16 + v_pk_max_f16 +
// v_dot2_f32_f16 = 3 VALU for 2 MACs (halves VALU vs fp32).
// LDS: 2 x [64 pair][64 i] h2 = 32 KB (+256 B w2) -> up to 4 blocks/CU.
// Per pair per thread: 2 x ds_read_b128 + 1 x ds_read_b32 (all broadcast-
// grouped, conflict-free) -> LDS bytes also halved vs fp32 version.
// grid: 8 bh x 8 it x 8 jt = 512 blocks.
// ---------------------------------------------------------------------------
__global__ __launch_bounds__(256) void score_kernel(
    const h2* __restrict__ qh_h, const h2* __restrict__ kh_h,
    const float* __restrict__ W2, const float* __restrict__ b2,
    float* __restrict__ out)
{
    const int bid = blockIdx.x;           // [0, 512)
    const int bh  = bid >> 6;
    const int it  = (bid >> 3) & 7;
    const int jt  = bid & 7;
    const int i0  = it * 64;
    const int j0  = jt * 64;

    __shared__ h2 qt2[NP][64];
    __shared__ h2 kt2[NP][64];
    __shared__ h2 w2h[NP];

    const int tid = threadIdx.x;
    // Stage both tiles: 2 x 64 rows x 16 float4 (256 B coalesced per row).
    for (int idx = tid; idx < 2 * NP * 16; idx += 256) {
        const int tile = idx >> 10;
        const int p    = (idx >> 4) & 63;
        const int g    = idx & 15;
        const h2* srcp = tile ? kh_h : qh_h;
        const int o0   = tile ? j0 : i0;
        float4 v = ((const float4*)(srcp + (size_t)(bh * NP + p) * T + o0))[g];
        if (tile) ((float4*)&kt2[p][0])[g] = v;
        else      ((float4*)&qt2[p][0])[g] = v;
    }
    if (tid < NP) {
        h2 w;
        w.x = (_Float16)W2[2 * tid];
        w.y = (_Float16)W2[2 * tid + 1];
        w2h[tid] = w;
    }
    __syncthreads();

    const int tx = tid & 15;              // j fragment
    const int ty = tid >> 4;              // i fragment

    float acc[4][4];
    #pragma unroll
    for (int m = 0; m < 4; ++m)
        #pragma unroll
        for (int n = 0; n < 4; ++n)
            acc[m][n] = 0.0f;

    const h2 hzero = (h2)(_Float16)0.0f;

    #pragma unroll 4
    for (int p = 0; p < NP; ++p) {
        const float4 qa4 = ((const float4*)&qt2[p][0])[ty];  // 4 h2, i=4ty..+3
        const float4 kb4 = ((const float4*)&kt2[p][0])[tx];  // 4 h2, j=4tx..+3
        const h2 w = w2h[p];
        h2 qa[4], kb[4];
        qa[0] = __builtin_bit_cast(h2, qa4.x);
        qa[1] = __builtin_bit_cast(h2, qa4.y);
        qa[2] = __builtin_bit_cast(h2, qa4.z);
        qa[3] = __builtin_bit_cast(h2, qa4.w);
        kb[0] = __builtin_bit_cast(h2, kb4.x);
        kb[1] = __builtin_bit_cast(h2, kb4.y);
        kb[2] = __builtin_bit_cast(h2, kb4.z);
        kb[3] = __builtin_bit_cast(h2, kb4.w);
#if !HAVE_FDOT2
        const float wx = (float)w.x, wy = (float)w.y;
#endif
        #pragma unroll
        for (int m = 0; m < 4; ++m) {
            #pragma unroll
            for (int n = 0; n < 4; ++n) {
                h2 u = qa[m] + kb[n];                       // v_pk_add_f16
                u = __builtin_elementwise_max(u, hzero);    // v_pk_max_f16
#if HAVE_FDOT2
                acc[m][n] = __builtin_amdgcn_fdot2(u, w, acc[m][n], false);
#else
                acc[m][n] += (float)u.x * wx + (float)u.y * wy;
#endif
            }
        }
    }

    const float bb = b2[0];
    #pragma unroll
    for (int m = 0; m < 4; ++m) {
        const int i = i0 + 4 * ty + m;
        float4 o;
        o.x = acc[m][0] + bb;
        o.y = acc[m][1] + bb;
        o.z = acc[m][2] + bb;
        o.w = acc[m][3] + bb;
        ((float4*)(out + (size_t)(bh * T + i) * T + j0))[tx] = o;
    }
}

extern "C" void kernel_launch(void* const* d_in, const int* in_sizes, int n_in,
                              void* d_out, int out_size, void* d_ws, size_t ws_size,
                              hipStream_t stream) {
    const float* q  = (const float*)d_in[0];
    const float* k  = (const float*)d_in[1];
    const float* W1 = (const float*)d_in[2];
    const float* b1 = (const float*)d_in[3];
    const float* W2 = (const float*)d_in[4];
    const float* b2 = (const float*)d_in[5];
    float* out = (float*)d_out;

    // Workspace: qh_h + kh_h as half2 pairs, each 8*64*512*4 B = 1 MB.
    h2* qh_h = (h2*)d_ws;
    h2* kh_h = qh_h + (size_t)NBH * NP * T;

    proj_kernel<<<256, 256, 0, stream>>>(q, k, W1, b1, qh_h, kh_h);
    score_kernel<<<512, 256, 0, stream>>>(qh_h, kh_h, W2, b2, out);
}

// Round 3
// 91.349 us; speedup vs baseline: 1.1935x; 1.0085x over previous
//
#include <hip/hip_runtime.h>

// Problem constants (B=2, H=4 -> NBH=8; Tq=Tk=512; D=64; HID=128)
#define T    512
#define D    64
#define HID  128
#define NBH  8
#define NP   (HID / 2)   // 64 c-pairs

typedef _Float16 h2 __attribute__((ext_vector_type(2)));

static __device__ __forceinline__ h2 bc_h2(float f) {
    return __builtin_bit_cast(h2, f);
}

// ---------------------------------------------------------------------------
// Phase A: qh[bh][c][i] = b1[c] + sum_d q[bh][i][d] * W1[d][c]   (src==0)
//          kh[bh][c][j] =         sum_d k[bh][j][d] * W1[64+d][c] (src==1)
// Output packed as h2 pairs over c: ws[bh][p][i], i contiguous.
// grid: 8 bh x 2 src x 8 row-chunks x 4 c-splits = 512 blocks (2/CU ->
// 2 waves/SIMD for latency hiding; R2 had 1 wave/SIMD here).
// ---------------------------------------------------------------------------
__global__ __launch_bounds__(256, 2) void proj_kernel(
    const float* __restrict__ q, const float* __restrict__ k,
    const float* __restrict__ W1, const float* __restrict__ b1,
    h2* __restrict__ qh_h, h2* __restrict__ kh_h)
{
    const int bid    = blockIdx.x;        // [0,512)
    const int bh     = bid >> 6;
    const int src    = (bid >> 5) & 1;
    const int chunk  = (bid >> 2) & 7;
    const int csplit = bid & 3;
    const int base_c = csplit * 32;       // 32 channels per block

    const float* __restrict__ X = (src == 0) ? q : k;
    h2* __restrict__ outp       = (src == 0) ? qh_h : kh_h;

    // 32 c-rows of W1, transposed to [cc][d]; stride 68 floats keeps 16 B
    // alignment (272 B) and breaks pow-2 bank stride on staging writes.
    __shared__ float w1t[32][68];

    const int tid = threadIdx.x;
    for (int idx = tid; idx < 32 * 64; idx += 256) {
        const int cc = idx & 31;          // consecutive -> coalesced global read
        const int d  = idx >> 5;
        w1t[cc][d] = W1[(src * D + d) * HID + base_c + cc];
    }
    __syncthreads();

    const int r  = tid & 63;              // lane -> row (stores coalesce)
    const int cg = tid >> 6;              // wave -> 8-c group (wave-uniform)
    const int i  = chunk * 64 + r;

    // This thread's input row in registers (64 VGPR).
    float xr[D];
    const float4* xrow = (const float4*)(X + (size_t)(bh * T + i) * D);
    #pragma unroll
    for (int t = 0; t < D / 4; ++t) {
        const float4 v = xrow[t];
        xr[4*t+0] = v.x; xr[4*t+1] = v.y; xr[4*t+2] = v.z; xr[4*t+3] = v.w;
    }

    #pragma unroll
    for (int pp = 0; pp < 4; ++pp) {
        const int cc0 = cg * 8 + 2 * pp;         // wave-uniform -> LDS broadcast
        float acc0 = (src == 0) ? b1[base_c + cc0]     : 0.0f;
        float acc1 = (src == 0) ? b1[base_c + cc0 + 1] : 0.0f;
        const float4* w0 = (const float4*)(&w1t[cc0][0]);
        const float4* w1 = (const float4*)(&w1t[cc0 + 1][0]);
        #pragma unroll
        for (int t = 0; t < D / 4; ++t) {
            const float4 a = w0[t];
            const float4 b = w1[t];
            acc0 += xr[4*t+0]*a.x + xr[4*t+1]*a.y + xr[4*t+2]*a.z + xr[4*t+3]*a.w;
            acc1 += xr[4*t+0]*b.x + xr[4*t+1]*b.y + xr[4*t+2]*b.z + xr[4*t+3]*b.w;
        }
        h2 v;
        v.x = (_Float16)acc0;
        v.y = (_Float16)acc1;
        const int p = csplit * 16 + cg * 4 + pp;  // global pair index [0,64)
        outp[(size_t)(bh * NP + p) * T + i] = v;  // lanes span i -> coalesced
    }
}

// ---------------------------------------------------------------------------
// Phase B: s[bh][i][j] = b2 + sum_c W2[c] * relu(qh[bh][c][i] + kh[bh][c][j])
// 64x64 tile, 256 threads, 4x4 fp32 acc/thread. Inner: per c-pair per (m,n):
// v_pk_add_f16 + v_pk_max_f16 + v_dot2_f32_f16 (3 VALU / 2 MACs).
// Explicit 1-deep software pipeline: q/k fragments for p+1 and the next
// w2 group (b128, amortized over 4 p) are in flight while p computes.
// Tiles padded +1 row so the prefetch needs no bounds branch.
// grid: 8 bh x 8 it x 8 jt = 512 blocks.
// ---------------------------------------------------------------------------
__global__ __launch_bounds__(256, 2) void score_kernel(
    const h2* __restrict__ qh_h, const h2* __restrict__ kh_h,
    const float* __restrict__ W2, const float* __restrict__ b2,
    float* __restrict__ out)
{
    const int bid = blockIdx.x;           // [0, 512)
    const int bh  = bid >> 6;
    const int it  = (bid >> 3) & 7;
    const int jt  = bid & 7;
    const int i0  = it * 64;
    const int j0  = jt * 64;

    __shared__ h2 qt2[NP + 1][64];        // +1 pad row: branch-free prefetch
    __shared__ h2 kt2[NP + 1][64];
    __shared__ h2 w2h[NP + 4];            // +4 pad pairs

    const int tid = threadIdx.x;
    // Stage both tiles: 2 x 64 rows x 16 float4 (256 B coalesced per row).
    for (int idx = tid; idx < 2 * NP * 16; idx += 256) {
        const int tile = idx >> 10;
        const int p    = (idx >> 4) & 63;
        const int g    = idx & 15;
        const h2* srcp = tile ? kh_h : qh_h;
        const int o0   = tile ? j0 : i0;
        float4 v = ((const float4*)(srcp + (size_t)(bh * NP + p) * T + o0))[g];
        if (tile) ((float4*)&kt2[p][0])[g] = v;
        else      ((float4*)&qt2[p][0])[g] = v;
    }
    if (tid < NP) {
        h2 w;
        w.x = (_Float16)W2[2 * tid];
        w.y = (_Float16)W2[2 * tid + 1];
        w2h[tid] = w;
    }
    __syncthreads();

    const int tx = tid & 15;              // j fragment
    const int ty = tid >> 4;              // i fragment

    const h2* __restrict__ qb = &qt2[0][4 * ty];  // row stride 64 h2 = 256 B
    const h2* __restrict__ kb = &kt2[0][4 * tx];

    float acc[4][4];
    #pragma unroll
    for (int m = 0; m < 4; ++m)
        #pragma unroll
        for (int n = 0; n < 4; ++n)
            acc[m][n] = 0.0f;

    const h2 hzero = (h2)(_Float16)0.0f;

    // Pipeline primers.
    float4 qf = *(const float4*)qb;
    float4 kf = *(const float4*)kb;
    float4 w4 = *(const float4*)&w2h[0];

    for (int pg = 0; pg < 16; ++pg) {
        // Prefetch next w-group (pad pairs for pg==15; value unused).
        const float4 w4n = *(const float4*)&w2h[4 * pg + 4];
        #pragma unroll
        for (int s = 0; s < 4; ++s) {
            const int p = 4 * pg + s;
            // Prefetch p+1 fragments (pad row for p==63; value unused).
            const float4 qn = *(const float4*)(qb + (size_t)(p + 1) * 64);
            const float4 kn = *(const float4*)(kb + (size_t)(p + 1) * 64);

            const h2 w = bc_h2(s == 0 ? w4.x : s == 1 ? w4.y
                             : s == 2 ? w4.z : w4.w);
            const h2 qv[4] = {bc_h2(qf.x), bc_h2(qf.y), bc_h2(qf.z), bc_h2(qf.w)};
            const h2 kv[4] = {bc_h2(kf.x), bc_h2(kf.y), bc_h2(kf.z), bc_h2(kf.w)};
            #pragma unroll
            for (int m = 0; m < 4; ++m) {
                #pragma unroll
                for (int n = 0; n < 4; ++n) {
                    h2 u = qv[m] + kv[n];                    // v_pk_add_f16
                    u = __builtin_elementwise_max(u, hzero); // v_pk_max_f16
                    acc[m][n] = __builtin_amdgcn_fdot2(u, w, acc[m][n], false);
                }
            }
            qf = qn;
            kf = kn;
        }
        w4 = w4n;
    }

    const float bb = b2[0];
    #pragma unroll
    for (int m = 0; m < 4; ++m) {
        const int i = i0 + 4 * ty + m;
        float4 o;
        o.x = acc[m][0] + bb;
        o.y = acc[m][1] + bb;
        o.z = acc[m][2] + bb;
        o.w = acc[m][3] + bb;
        ((float4*)(out + (size_t)(bh * T + i) * T + j0))[tx] = o;
    }
}

extern "C" void kernel_launch(void* const* d_in, const int* in_sizes, int n_in,
                              void* d_out, int out_size, void* d_ws, size_t ws_size,
                              hipStream_t stream) {
    const float* q  = (const float*)d_in[0];
    const float* k  = (const float*)d_in[1];
    const float* W1 = (const float*)d_in[2];
    const float* b1 = (const float*)d_in[3];
    const float* W2 = (const float*)d_in[4];
    const float* b2 = (const float*)d_in[5];
    float* out = (float*)d_out;

    // Workspace: qh_h + kh_h as h2 pairs, each 8*64*512*4 B = 1 MB.
    h2* qh_h = (h2*)d_ws;
    h2* kh_h = qh_h + (size_t)NBH * NP * T;

    proj_kernel<<<512, 256, 0, stream>>>(q, k, W1, b1, qh_h, kh_h);
    score_kernel<<<512, 256, 0, stream>>>(qh_h, kh_h, W2, b2, out);
}